// Round 2
// baseline (505.568 us; speedup 1.0000x reference)
//
#include <hip/hip_runtime.h>
#include <math.h>

#define BB 8
#define CC 512
#define KK 19
#define HWHW 16384
#define INV_HW (1.0f/16384.0f)

typedef __attribute__((ext_vector_type(8))) short bf16x8;
typedef __attribute__((ext_vector_type(4))) short s16x4;
typedef __attribute__((ext_vector_type(4))) float f32x4;

__device__ __forceinline__ unsigned short f2bf(float f) {
    unsigned int u = __float_as_uint(f);
    u = (u + 0x7fffu + ((u >> 16) & 1u)) >> 16;
    return (unsigned short)u;
}

// pack 2 floats -> 2 bf16 (RNE, identical to f2bf) in one instruction
__device__ __forceinline__ unsigned int pk_bf16(float a, float b) {
    unsigned int r;
    asm("v_cvt_pk_bf16_f32 %0, %1, %2" : "=v"(r) : "v"(a), "v"(b));
    return r;
}

// ================= k_s1: mask = sigmoid(Wm @ x + bm), bf16 out ==============
// ALSO relays x as bf16 in two pre-swizzled tile-contiguous layouts:
//   xt4g: [b][ptile128][cs8] 16KB tiles, [p][c]-frag layout (for k_s4)
//   xt2g: [b][ct8][s16][kp16] 8KB tiles, [c][p]-frag layout (for k_s2)
// so downstream kernels read fully-contiguous bf16 tiles (no 512B strips).
__global__ __launch_bounds__(256, 3) void k_s1(const float* __restrict__ x,
                                               const float* __restrict__ Wm,
                                               const float* __restrict__ bm,
                                               unsigned short* __restrict__ mask,
                                               unsigned short* __restrict__ xt4g,
                                               unsigned short* __restrict__ xt2g) {
    __shared__ short wm[20 * CC];
    __shared__ short xt[2][128 * 64];
    const int tid = threadIdx.x;
    const int b = blockIdx.x >> 7;
    const int pt = blockIdx.x & 127;
    const int p0 = pt << 7;
    const float* xb = x + ((size_t)b * CC) * HWHW + p0;

    for (int u = tid; u < 20 * 128; u += 256) {
        const int k = u >> 7;
        const int c4 = (u & 127) << 2;
        float4 w = {0.f, 0.f, 0.f, 0.f};
        if (k < KK) w = *(const float4*)(Wm + k * CC + c4);
        s16x4 v = { (short)f2bf(w.x), (short)f2bf(w.y), (short)f2bf(w.z), (short)f2bf(w.w) };
        *(s16x4*)&wm[(k << 9) + (((c4 >> 3) ^ (k & 7)) << 3) + (c4 & 7)] = v;
    }

    const int wv = tid >> 6, ln = tid & 63;
    const int lm = ln & 15, q = ln >> 4;
    const f32x4 zz = {0.f, 0.f, 0.f, 0.f};
    f32x4 acc[2][2];
    acc[0][0] = zz; acc[0][1] = zz; acc[1][0] = zz; acc[1][1] = zz;

    const int cg0 = tid >> 5;            // 0..7  (h=0 c-group; h=1 adds 8)
    const int pA  = (tid & 31) << 2;     // 0..124
    const int pqT = (tid & 31) & 15;     // p-quad within 64-p chunk
    const int sS  = pt >> 3;             // s-slice index (1024-p)
    const int kpT = ((pt & 7) << 1) | ((tid & 31) >> 4);  // 64-p chunk in slice
    const float* sA = xb + (size_t)(cg0 << 2) * HWHW + pA;
    const float* sB = xb + (size_t)((cg0 + 8) << 2) * HWHW + pA;
    unsigned short* t4fix = xt4g + ((size_t)((b << 7) | pt) << 16);
    unsigned short* t2fix = xt2g + ((size_t)(b << 3) << 20)
                                 + ((size_t)((sS << 4) | kpT) << 12);

    float4 Fa[8], Fb[8];
#pragma unroll
    for (int j = 0; j < 4; ++j) {
        Fa[j]     = *(const float4*)(sA + (size_t)j * HWHW);
        Fa[4 + j] = *(const float4*)(sB + (size_t)j * HWHW);
    }

#pragma unroll
    for (int cs = 0; cs < 8; ++cs) {
        const float4* cur = (cs & 1) ? Fb : Fa;
        float4* nxt = (cs & 1) ? Fa : Fb;
        if (cs < 7) {                               // issue next tile EARLY
            const size_t co = (size_t)((cs + 1) << 6) * HWHW;
#pragma unroll
            for (int j = 0; j < 4; ++j) {
                nxt[j]     = *(const float4*)(sA + co + (size_t)j * HWHW);
                nxt[4 + j] = *(const float4*)(sB + co + (size_t)j * HWHW);
            }
        }
        short* xts = (short*)xt[cs & 1];
        unsigned short* t4 = t4fix + ((size_t)cs << 13);
        unsigned short* t2 = t2fix + ((size_t)cs << 20);
#pragma unroll
        for (int h = 0; h < 2; ++h) {
            const int cg = cg0 + (h << 3);
            const float* G0 = (const float*)&cur[(h << 2) + 0];
            const float* G1 = (const float*)&cur[(h << 2) + 1];
            const float* G2 = (const float*)&cur[(h << 2) + 2];
            const float* G3 = (const float*)&cur[(h << 2) + 3];
#pragma unroll
            for (int j = 0; j < 4; ++j) {           // [p][c]-frag: LDS + xt4g
                const int pr = pA + j;
                uint2 v = make_uint2(pk_bf16(G0[j], G1[j]), pk_bf16(G2[j], G3[j]));
                const int idx = (pr << 6) + (((cg >> 1) ^ (pr & 7)) << 3) + ((cg & 1) << 2);
                *(uint2*)&xts[idx] = v;
                *(uint2*)&t4[idx] = v;
            }
#pragma unroll
            for (int rr = 0; rr < 4; ++rr) {        // [c][p]-frag: xt2g
                const int cl = (cg << 2) + rr;
                const float* Gr = (const float*)&cur[(h << 2) + rr];
                uint2 w = make_uint2(pk_bf16(Gr[0], Gr[1]), pk_bf16(Gr[2], Gr[3]));
                const int idx2 = (cl << 6) + (((pqT >> 1) ^ (cl & 7)) << 3) + ((pqT & 1) << 2);
                *(uint2*)&t2[idx2] = w;
            }
        }
        asm volatile("s_waitcnt lgkmcnt(0)" ::: "memory");
        __builtin_amdgcn_s_barrier();
        asm volatile("" ::: "memory");
#pragma unroll
        for (int ks = 0; ks < 2; ++ks) {
            const int gch = (cs << 3) + (ks << 2) + q;
            const int m1 = (lm < 3) ? (16 + lm) : 19;
            bf16x8 a0 = *(const bf16x8*)&wm[(lm << 9) + ((gch ^ (lm & 7)) << 3)];
            bf16x8 a1 = *(const bf16x8*)&wm[(m1 << 9) + ((gch ^ (m1 & 7)) << 3)];
            const int lch = (ks << 2) + q;
#pragma unroll
            for (int nt = 0; nt < 2; ++nt) {
                const int pr = (((wv << 1) + nt) << 4) + lm;
                bf16x8 bv = *(const bf16x8*)&xts[(pr << 6) + ((lch ^ (pr & 7)) << 3)];
                acc[0][nt] = __builtin_amdgcn_mfma_f32_16x16x32_bf16(a0, bv, acc[0][nt], 0, 0, 0);
                acc[1][nt] = __builtin_amdgcn_mfma_f32_16x16x32_bf16(a1, bv, acc[1][nt], 0, 0, 0);
            }
        }
    }

    unsigned short* mb = mask + ((size_t)b * KK) * HWHW + p0;
#pragma unroll
    for (int mt = 0; mt < 2; ++mt)
#pragma unroll
        for (int r = 0; r < 4; ++r) {
            const int k = (mt << 4) + (q << 2) + r;
            if (k < KK) {
                const float bias = bm[k];
#pragma unroll
                for (int nt = 0; nt < 2; ++nt) {
                    const int p = (((wv << 1) + nt) << 4) + lm;
                    const float t = acc[mt][nt][r] + bias;
                    mb[(size_t)k * HWHW + p] = f2bf(1.0f / (1.0f + __expf(-t)));
                }
            }
        }
}

// ====== k_s2: cf_part[s][b][k][c] = sum_{p in slice} mask[k][p]*x[c][p] =====
// x comes from xt2g: pre-swizzled 8KB tiles, read contiguously, raw LDS copy.
__global__ __launch_bounds__(256, 4) void k_s2(const unsigned short* __restrict__ xt2g,
                                               const unsigned short* __restrict__ mask,
                                               float* __restrict__ cf_part) {
    __shared__ short mt_[2][20 * 64];
    __shared__ short xtl[2][64 * 64];
    const int tid = threadIdx.x;
    const int s = blockIdx.x & 15;
    const int ct = (blockIdx.x >> 4) & 7;
    const int b = blockIdx.x >> 7;
    const int wv = tid >> 6, ln = tid & 63;
    const int lm = ln & 15, q = ln >> 4;
    const unsigned short* mbs = mask + ((size_t)b * KK) * HWHW + (s << 10);
    const unsigned short* tb = xt2g + ((size_t)((((b << 3) | ct) << 4) | s) << 16);

    const int mk = tid >> 3, mch = tid & 7;   // mask-stage coords (tid<160)

    const f32x4 zz = {0.f, 0.f, 0.f, 0.f};
    f32x4 acc[2];
    acc[0] = zz; acc[1] = zz;

    uint4 Xa[2], Xb2[2];
    uint4 Ma = make_uint4(0u,0u,0u,0u), Mb = make_uint4(0u,0u,0u,0u);

    if (tid < 160 && mk < KK) Ma = *(const uint4*)(mbs + (size_t)mk * HWHW + (mch << 3));
    Xa[0] = *(const uint4*)(tb + (tid << 4));
    Xa[1] = *(const uint4*)(tb + (tid << 4) + 8);

#pragma unroll
    for (int kp = 0; kp < 16; ++kp) {
        const uint4* curX = (kp & 1) ? Xb2 : Xa;
        uint4* nxtX = (kp & 1) ? Xa : Xb2;
        const uint4 curM = (kp & 1) ? Mb : Ma;
        uint4* nxtM = (kp & 1) ? &Ma : &Mb;
        if (kp < 15) {                            // issue next tile EARLY
            if (tid < 160 && mk < KK)
                *nxtM = *(const uint4*)(mbs + (size_t)mk * HWHW + ((kp + 1) << 6) + (mch << 3));
            nxtX[0] = *(const uint4*)(tb + ((kp + 1) << 12) + (tid << 4));
            nxtX[1] = *(const uint4*)(tb + ((kp + 1) << 12) + (tid << 4) + 8);
        }
        short* mts = (short*)mt_[kp & 1];
        short* xls = (short*)xtl[kp & 1];
        if (tid < 160)
            *(uint4*)&mts[(mk << 6) + ((mch ^ (mk & 7)) << 3)] = curM;
        *(uint4*)&xls[(tid << 4)] = curX[0];
        *(uint4*)&xls[(tid << 4) + 8] = curX[1];
        asm volatile("s_waitcnt lgkmcnt(0)" ::: "memory");
        __builtin_amdgcn_s_barrier();
        asm volatile("" ::: "memory");
#pragma unroll
        for (int ks = 0; ks < 2; ++ks) {
            const int pch = (ks << 2) + q;
            const int cr = (wv << 4) + lm;
            bf16x8 bv = *(const bf16x8*)&xls[(cr << 6) + ((pch ^ (cr & 7)) << 3)];
            const int m1 = (lm < 3) ? (16 + lm) : 19;
            bf16x8 a0 = *(const bf16x8*)&mts[(lm << 6) + ((pch ^ (lm & 7)) << 3)];
            bf16x8 a1 = *(const bf16x8*)&mts[(m1 << 6) + ((pch ^ (m1 & 7)) << 3)];
            acc[0] = __builtin_amdgcn_mfma_f32_16x16x32_bf16(a0, bv, acc[0], 0, 0, 0);
            acc[1] = __builtin_amdgcn_mfma_f32_16x16x32_bf16(a1, bv, acc[1], 0, 0, 0);
        }
    }

    float* dst = cf_part + ((size_t)(s * BB + b) * KK) * CC + (ct << 6) + (wv << 4) + lm;
#pragma unroll
    for (int mt = 0; mt < 2; ++mt)
#pragma unroll
        for (int r = 0; r < 4; ++r) {
            const int k = (mt << 4) + (q << 2) + r;
            if (k < KK) dst[(size_t)k * CC] = acc[mt][r];
        }
}

// ========== k_s2r: cf = INV_HW * sum_s cf_part ==========
__global__ __launch_bounds__(256) void k_s2r(const float* __restrict__ part,
                                             float* __restrict__ cf) {
    const int i = blockIdx.x * 256 + threadIdx.x;
    if (i >= BB * KK * CC) return;
    const int b = i / (KK * CC);
    const int rem = i - b * (KK * CC);
    float sum = 0.0f;
#pragma unroll
    for (int s = 0; s < 16; ++s)
        sum += part[((size_t)(s * BB + b) * KK) * CC + rem];
    cf[i] = sum * INV_HW;
}

// ====== k_filters: fil[b,k,o] = sum_c Wf[k,o,c]*cf[b,k,c] + bf[k,o] ======
__global__ __launch_bounds__(256) void k_filters(const float* __restrict__ Wf,
                                                 const float* __restrict__ bf,
                                                 const float* __restrict__ cf,
                                                 float* __restrict__ fil) {
    const int blk = blockIdx.x;
    const int k = blk >> 7;
    const int o = ((blk & 127) << 2) + (threadIdx.x >> 6);
    const int lane = threadIdx.x & 63;
    const float* wrow = Wf + ((size_t)k * CC + o) * CC;

    float acc[BB];
#pragma unroll
    for (int b = 0; b < BB; ++b) acc[b] = 0.0f;
#pragma unroll
    for (int j = 0; j < CC / 64; ++j) {
        const int c = lane + (j << 6);
        const float wv = wrow[c];
#pragma unroll
        for (int b = 0; b < BB; ++b)
            acc[b] += wv * cf[((size_t)b * KK + k) * CC + c];
    }
#pragma unroll
    for (int b = 0; b < BB; ++b) {
#pragma unroll
        for (int off = 32; off > 0; off >>= 1)
            acc[b] += __shfl_down(acc[b], off, 64);
    }
    if (lane == 0) {
        const float bias = bf[k * CC + o];
#pragma unroll
        for (int b = 0; b < BB; ++b)
            fil[((size_t)b * KK + k) * CC + o] = acc[b] + bias;
    }
}

// ================= k_s4: pred = fil[b] @ x, fp32 out ==============
// x comes from xt4g: pre-swizzled 16KB tiles, read contiguously, raw LDS copy.
__global__ __launch_bounds__(256, 3) void k_s4(const unsigned short* __restrict__ xt4g,
                                               const float* __restrict__ fil,
                                               float* __restrict__ out) {
    __shared__ short wm[20 * CC];
    __shared__ short xt[2][128 * 64];
    const int tid = threadIdx.x;
    const int b = blockIdx.x >> 7;
    const int pt = blockIdx.x & 127;
    const int p0 = pt << 7;
    const float* fb = fil + ((size_t)b * KK) * CC;
    const unsigned short* tb = xt4g + ((size_t)((b << 7) | pt) << 16);

    for (int u = tid; u < 20 * 128; u += 256) {
        const int k = u >> 7;
        const int c4 = (u & 127) << 2;
        float4 w = {0.f, 0.f, 0.f, 0.f};
        if (k < KK) w = *(const float4*)(fb + k * CC + c4);
        s16x4 v = { (short)f2bf(w.x), (short)f2bf(w.y), (short)f2bf(w.z), (short)f2bf(w.w) };
        *(s16x4*)&wm[(k << 9) + (((c4 >> 3) ^ (k & 7)) << 3) + (c4 & 7)] = v;
    }

    const int wv = tid >> 6, ln = tid & 63;
    const int lm = ln & 15, q = ln >> 4;
    const f32x4 zz = {0.f, 0.f, 0.f, 0.f};
    f32x4 acc[2][2];
    acc[0][0] = zz; acc[0][1] = zz; acc[1][0] = zz; acc[1][1] = zz;

    uint4 Ta[4], Tb4[4];
#pragma unroll
    for (int r = 0; r < 4; ++r)
        Ta[r] = *(const uint4*)(tb + (tid << 5) + (r << 3));

#pragma unroll
    for (int cs = 0; cs < 8; ++cs) {
        const uint4* cur = (cs & 1) ? Tb4 : Ta;
        uint4* nxt = (cs & 1) ? Ta : Tb4;
        if (cs < 7) {                               // issue next tile EARLY
#pragma unroll
            for (int r = 0; r < 4; ++r)
                nxt[r] = *(const uint4*)(tb + ((cs + 1) << 13) + (tid << 5) + (r << 3));
        }
        short* xts = (short*)xt[cs & 1];
#pragma unroll
        for (int r = 0; r < 4; ++r)
            *(uint4*)&xts[(tid << 5) + (r << 3)] = cur[r];
        asm volatile("s_waitcnt lgkmcnt(0)" ::: "memory");
        __builtin_amdgcn_s_barrier();
        asm volatile("" ::: "memory");
#pragma unroll
        for (int ks = 0; ks < 2; ++ks) {
            const int gch = (cs << 3) + (ks << 2) + q;
            const int m1 = (lm < 3) ? (16 + lm) : 19;
            bf16x8 a0 = *(const bf16x8*)&wm[(lm << 9) + ((gch ^ (lm & 7)) << 3)];
            bf16x8 a1 = *(const bf16x8*)&wm[(m1 << 9) + ((gch ^ (m1 & 7)) << 3)];
            const int lch = (ks << 2) + q;
#pragma unroll
            for (int nt = 0; nt < 2; ++nt) {
                const int pr = (((wv << 1) + nt) << 4) + lm;
                bf16x8 bv = *(const bf16x8*)&xts[(pr << 6) + ((lch ^ (pr & 7)) << 3)];
                acc[0][nt] = __builtin_amdgcn_mfma_f32_16x16x32_bf16(a0, bv, acc[0][nt], 0, 0, 0);
                acc[1][nt] = __builtin_amdgcn_mfma_f32_16x16x32_bf16(a1, bv, acc[1][nt], 0, 0, 0);
            }
        }
    }

    float* ob = out + ((size_t)b * KK) * HWHW + p0;
#pragma unroll
    for (int mt = 0; mt < 2; ++mt)
#pragma unroll
        for (int r = 0; r < 4; ++r) {
            const int k = (mt << 4) + (q << 2) + r;
            if (k < KK) {
#pragma unroll
                for (int nt = 0; nt < 2; ++nt) {
                    const int p = (((wv << 1) + nt) << 4) + lm;
                    ob[(size_t)k * HWHW + p] = acc[mt][nt][r];
                }
            }
        }
}

extern "C" void kernel_launch(void* const* d_in, const int* in_sizes, int n_in,
                              void* d_out, int out_size, void* d_ws, size_t ws_size,
                              hipStream_t stream) {
    const float* x  = (const float*)d_in[0];
    const float* Wm = (const float*)d_in[1];
    const float* bm = (const float*)d_in[2];
    const float* Wf = (const float*)d_in[3];
    const float* bf = (const float*)d_in[4];
    float* out = (float*)d_out;

    char* p = (char*)d_ws;
    unsigned short* mask = (unsigned short*)p;  p += (size_t)BB * KK * HWHW * 2;   // 4.98 MB
    float* cf_part = (float*)p;                 p += (size_t)16 * BB * KK * CC * 4; // 4.98 MB
    float* cf  = (float*)p;                     p += (size_t)BB * KK * CC * 4;      // 311 KB
    float* fil = (float*)p;                     p += (size_t)BB * KK * CC * 4;      // 311 KB
    unsigned short* xt4g = (unsigned short*)p;  p += (size_t)BB * 128 * 8 * 16384;  // 134 MB
    unsigned short* xt2g = (unsigned short*)p;                                      // 134 MB

    k_s1<<<1024, 256, 0, stream>>>(x, Wm, bm, mask, xt4g, xt2g);
    k_s2<<<1024, 256, 0, stream>>>(xt2g, mask, cf_part);
    k_s2r<<<(BB * KK * CC + 255) / 256, 256, 0, stream>>>(cf_part, cf);
    k_filters<<<KK * 128, 256, 0, stream>>>(Wf, bf, cf, fil);
    k_s4<<<1024, 256, 0, stream>>>(xt4g, fil, out);
}

// Round 3
// 460.247 us; speedup vs baseline: 1.0985x; 1.0985x over previous
//
#include <hip/hip_runtime.h>
#include <math.h>

#define BB 8
#define CC 512
#define KK 19
#define HWHW 16384
#define INV_HW (1.0f/16384.0f)

typedef __attribute__((ext_vector_type(8))) short bf16x8;
typedef __attribute__((ext_vector_type(4))) short s16x4;
typedef __attribute__((ext_vector_type(4))) float f32x4;

__device__ __forceinline__ unsigned short f2bf(float f) {
    unsigned int u = __float_as_uint(f);
    u = (u + 0x7fffu + ((u >> 16) & 1u)) >> 16;
    return (unsigned short)u;
}

// pack 2 floats -> 2 bf16 (RNE, identical to f2bf) in one instruction
__device__ __forceinline__ unsigned int pk_bf16(float a, float b) {
    unsigned int r;
    asm("v_cvt_pk_bf16_f32 %0, %1, %2" : "=v"(r) : "v"(a), "v"(b));
    return r;
}

// ================= k_s1: mask = sigmoid(Wm @ x + bm), bf16 out ==============
// Relays x as bf16 tiles xt4g[b][pt][cs]: 16KB each, [p][c]-frag swizzled —
// written via LDS->global COALESCED copy (the R2 version wrote scattered 8B
// uint2s from registers: 8x write amplification; this was the R2 regression).
// Element map inside a tile: short_off(p,c) = (p<<6) + (((c>>3)^(p&7))<<3) + (c&7)
__global__ __launch_bounds__(256, 3) void k_s1(const float* __restrict__ x,
                                               const float* __restrict__ Wm,
                                               const float* __restrict__ bm,
                                               unsigned short* __restrict__ mask,
                                               unsigned short* __restrict__ xt4g) {
    __shared__ short wm[20 * CC];
    __shared__ short xt[2][128 * 64];
    const int tid = threadIdx.x;
    const int b = blockIdx.x >> 7;
    const int pt = blockIdx.x & 127;
    const int p0 = pt << 7;
    const float* xb = x + ((size_t)b * CC) * HWHW + p0;

    for (int u = tid; u < 20 * 128; u += 256) {
        const int k = u >> 7;
        const int c4 = (u & 127) << 2;
        float4 w = {0.f, 0.f, 0.f, 0.f};
        if (k < KK) w = *(const float4*)(Wm + k * CC + c4);
        s16x4 v = { (short)f2bf(w.x), (short)f2bf(w.y), (short)f2bf(w.z), (short)f2bf(w.w) };
        *(s16x4*)&wm[(k << 9) + (((c4 >> 3) ^ (k & 7)) << 3) + (c4 & 7)] = v;
    }

    const int wv = tid >> 6, ln = tid & 63;
    const int lm = ln & 15, q = ln >> 4;
    const f32x4 zz = {0.f, 0.f, 0.f, 0.f};
    f32x4 acc[2][2];
    acc[0][0] = zz; acc[0][1] = zz; acc[1][0] = zz; acc[1][1] = zz;

    const int cg0 = tid >> 5;            // 0..7  (h=0 c-group; h=1 adds 8)
    const int pA  = (tid & 31) << 2;     // 0..124
    const float* sA = xb + (size_t)(cg0 << 2) * HWHW + pA;
    const float* sB = xb + (size_t)((cg0 + 8) << 2) * HWHW + pA;
    unsigned short* t4fix = xt4g + ((size_t)((b << 7) | pt) << 16);

    float4 Fa[8], Fb[8];
#pragma unroll
    for (int j = 0; j < 4; ++j) {
        Fa[j]     = *(const float4*)(sA + (size_t)j * HWHW);
        Fa[4 + j] = *(const float4*)(sB + (size_t)j * HWHW);
    }

#pragma unroll
    for (int cs = 0; cs < 8; ++cs) {
        const float4* cur = (cs & 1) ? Fb : Fa;
        float4* nxt = (cs & 1) ? Fa : Fb;
        if (cs < 7) {                               // issue next tile EARLY
            const size_t co = (size_t)((cs + 1) << 6) * HWHW;
#pragma unroll
            for (int j = 0; j < 4; ++j) {
                nxt[j]     = *(const float4*)(sA + co + (size_t)j * HWHW);
                nxt[4 + j] = *(const float4*)(sB + co + (size_t)j * HWHW);
            }
        }
        short* xts = (short*)xt[cs & 1];
#pragma unroll
        for (int h = 0; h < 2; ++h) {
            const int cg = cg0 + (h << 3);
            const float* G0 = (const float*)&cur[(h << 2) + 0];
            const float* G1 = (const float*)&cur[(h << 2) + 1];
            const float* G2 = (const float*)&cur[(h << 2) + 2];
            const float* G3 = (const float*)&cur[(h << 2) + 3];
#pragma unroll
            for (int j = 0; j < 4; ++j) {           // [p][c]-frag LDS tile
                const int pr = pA + j;
                uint2 v = make_uint2(pk_bf16(G0[j], G1[j]), pk_bf16(G2[j], G3[j]));
                const int idx = (pr << 6) + (((cg >> 1) ^ (pr & 7)) << 3) + ((cg & 1) << 2);
                *(uint2*)&xts[idx] = v;
            }
        }
        asm volatile("s_waitcnt lgkmcnt(0)" ::: "memory");
        __builtin_amdgcn_s_barrier();
        asm volatile("" ::: "memory");
#pragma unroll
        for (int ks = 0; ks < 2; ++ks) {
            const int gch = (cs << 3) + (ks << 2) + q;
            const int m1 = (lm < 3) ? (16 + lm) : 19;
            bf16x8 a0 = *(const bf16x8*)&wm[(lm << 9) + ((gch ^ (lm & 7)) << 3)];
            bf16x8 a1 = *(const bf16x8*)&wm[(m1 << 9) + ((gch ^ (m1 & 7)) << 3)];
            const int lch = (ks << 2) + q;
#pragma unroll
            for (int nt = 0; nt < 2; ++nt) {
                const int pr = (((wv << 1) + nt) << 4) + lm;
                bf16x8 bv = *(const bf16x8*)&xts[(pr << 6) + ((lch ^ (pr & 7)) << 3)];
                acc[0][nt] = __builtin_amdgcn_mfma_f32_16x16x32_bf16(a0, bv, acc[0][nt], 0, 0, 0);
                acc[1][nt] = __builtin_amdgcn_mfma_f32_16x16x32_bf16(a1, bv, acc[1][nt], 0, 0, 0);
            }
        }
        // coalesced tile relay: LDS raw image -> global (16KB, 64B/thread)
        {
            unsigned short* t4 = t4fix + ((size_t)cs << 13);
#pragma unroll
            for (int r = 0; r < 4; ++r) {
                uint4 v = *(const uint4*)&xts[(r << 11) + (tid << 3)];
                *(uint4*)(t4 + (r << 11) + (tid << 3)) = v;
            }
        }
    }

    unsigned short* mb = mask + ((size_t)b * KK) * HWHW + p0;
#pragma unroll
    for (int mt = 0; mt < 2; ++mt)
#pragma unroll
        for (int r = 0; r < 4; ++r) {
            const int k = (mt << 4) + (q << 2) + r;
            if (k < KK) {
                const float bias = bm[k];
#pragma unroll
                for (int nt = 0; nt < 2; ++nt) {
                    const int p = (((wv << 1) + nt) << 4) + lm;
                    const float t = acc[mt][nt][r] + bias;
                    mb[(size_t)k * HWHW + p] = f2bf(1.0f / (1.0f + __expf(-t)));
                }
            }
        }
}

// ====== k_s2: cf_part[ptg][b][k][c] = sum_{p in 1024-slice} m[k][p]*x[c][p] ==
// Consumes xt4g [p][c]-frag tiles: coalesced 16KB load -> raw LDS copy ->
// per-lane inverse-swizzle gather (8x ds_read_u16) builds [c][p] B-frags.
// Same 32-p MFMA grouping/order as before -> bit-identical cf.
__global__ __launch_bounds__(256, 3) void k_s2(const unsigned short* __restrict__ xt4g,
                                               const unsigned short* __restrict__ mask,
                                               float* __restrict__ cf_part) {
    __shared__ short xls[2][8192];
    __shared__ short mtl[2][20 * 128];
    const int tid = threadIdx.x;
    const int cs = blockIdx.x & 7;           // c-chunk (64 c)
    const int ptg = (blockIdx.x >> 3) & 15;  // 1024-p slice = 8 tiles
    const int b = blockIdx.x >> 7;
    const int wv = tid >> 6, ln = tid & 63;
    const int lm = ln & 15, q = ln >> 4;

    const unsigned short* mb = mask + ((size_t)b * KK) * HWHW + (ptg << 10);
    const unsigned short* tbase = xt4g + (((size_t)(((b << 4) | ptg) << 6) + cs) << 13);

    const int mu1 = tid + 256;
    const int k0 = tid >> 4, ch0 = tid & 15;
    const int k1 = mu1 >> 4, ch1 = mu1 & 15;

    const f32x4 zz = {0.f, 0.f, 0.f, 0.f};
    f32x4 acc[2];
    acc[0] = zz; acc[1] = zz;

    uint4 Xa[4], Xb[4], Ma[2], Mb[2];
    const uint4 z4 = make_uint4(0u, 0u, 0u, 0u);

#pragma unroll
    for (int r = 0; r < 4; ++r) Xa[r] = *(const uint4*)(tbase + (r << 11) + (tid << 3));
    Ma[0] = z4; Ma[1] = z4;
    if (k0 < KK) Ma[0] = *(const uint4*)(mb + (size_t)k0 * HWHW + (ch0 << 3));
    if (mu1 < 320 && k1 < KK) Ma[1] = *(const uint4*)(mb + (size_t)k1 * HWHW + (ch1 << 3));

#pragma unroll
    for (int t = 0; t < 8; ++t) {
        const uint4* curX = (t & 1) ? Xb : Xa;
        uint4* nxtX = (t & 1) ? Xa : Xb;
        const uint4* curM = (t & 1) ? Mb : Ma;
        uint4* nxtM = (t & 1) ? Ma : Mb;
        if (t < 7) {                              // issue next tile EARLY
            const unsigned short* tp = tbase + ((size_t)(t + 1) << 16);
#pragma unroll
            for (int r = 0; r < 4; ++r) nxtX[r] = *(const uint4*)(tp + (r << 11) + (tid << 3));
            nxtM[0] = z4; nxtM[1] = z4;
            if (k0 < KK) nxtM[0] = *(const uint4*)(mb + (size_t)k0 * HWHW + ((t + 1) << 7) + (ch0 << 3));
            if (mu1 < 320 && k1 < KK) nxtM[1] = *(const uint4*)(mb + (size_t)k1 * HWHW + ((t + 1) << 7) + (ch1 << 3));
        }
        short* xl = (short*)xls[t & 1];
        short* ml = (short*)mtl[t & 1];
#pragma unroll
        for (int r = 0; r < 4; ++r) *(uint4*)&xl[(r << 11) + (tid << 3)] = curX[r];
        *(uint4*)&ml[(k0 << 7) + ((ch0 ^ (k0 & 7)) << 3)] = curM[0];
        if (mu1 < 320)
            *(uint4*)&ml[(k1 << 7) + ((ch1 ^ (k1 & 7)) << 3)] = curM[1];
        asm volatile("s_waitcnt lgkmcnt(0)" ::: "memory");
        __builtin_amdgcn_s_barrier();
        asm volatile("" ::: "memory");
        const int c = (wv << 4) + lm;
        const int m1 = (lm < 3) ? (16 + lm) : 19;
#pragma unroll
        for (int cc = 0; cc < 4; ++cc) {
            const int pb = (cc << 5) + (q << 3);   // lane's 8-p run (pb%8==0)
            short e[8];
#pragma unroll
            for (int i = 0; i < 8; ++i)
                e[i] = xl[((pb + i) << 6) + (((c >> 3) ^ i) << 3) + (c & 7)];
            bf16x8 bv = {e[0], e[1], e[2], e[3], e[4], e[5], e[6], e[7]};
            const int pg = (cc << 2) + q;
            bf16x8 a0 = *(const bf16x8*)&ml[(lm << 7) + ((pg ^ (lm & 7)) << 3)];
            bf16x8 a1 = *(const bf16x8*)&ml[(m1 << 7) + ((pg ^ (m1 & 7)) << 3)];
            acc[0] = __builtin_amdgcn_mfma_f32_16x16x32_bf16(a0, bv, acc[0], 0, 0, 0);
            acc[1] = __builtin_amdgcn_mfma_f32_16x16x32_bf16(a1, bv, acc[1], 0, 0, 0);
        }
    }

    float* dst = cf_part + ((size_t)(ptg * BB + b) * KK) * CC + (cs << 6) + (wv << 4) + lm;
#pragma unroll
    for (int mt = 0; mt < 2; ++mt)
#pragma unroll
        for (int r = 0; r < 4; ++r) {
            const int k = (mt << 4) + (q << 2) + r;
            if (k < KK) dst[(size_t)k * CC] = acc[mt][r];
        }
}

// ========== k_s2r: cf = INV_HW * sum_s cf_part ==========
__global__ __launch_bounds__(256) void k_s2r(const float* __restrict__ part,
                                             float* __restrict__ cf) {
    const int i = blockIdx.x * 256 + threadIdx.x;
    if (i >= BB * KK * CC) return;
    const int b = i / (KK * CC);
    const int rem = i - b * (KK * CC);
    float sum = 0.0f;
#pragma unroll
    for (int s = 0; s < 16; ++s)
        sum += part[((size_t)(s * BB + b) * KK) * CC + rem];
    cf[i] = sum * INV_HW;
}

// ====== k_filters: fil[b,k,o] = sum_c Wf[k,o,c]*cf[b,k,c] + bf[k,o] ======
__global__ __launch_bounds__(256) void k_filters(const float* __restrict__ Wf,
                                                 const float* __restrict__ bf,
                                                 const float* __restrict__ cf,
                                                 float* __restrict__ fil) {
    const int blk = blockIdx.x;
    const int k = blk >> 7;
    const int o = ((blk & 127) << 2) + (threadIdx.x >> 6);
    const int lane = threadIdx.x & 63;
    const float* wrow = Wf + ((size_t)k * CC + o) * CC;

    float acc[BB];
#pragma unroll
    for (int b = 0; b < BB; ++b) acc[b] = 0.0f;
#pragma unroll
    for (int j = 0; j < CC / 64; ++j) {
        const int c = lane + (j << 6);
        const float wv = wrow[c];
#pragma unroll
        for (int b = 0; b < BB; ++b)
            acc[b] += wv * cf[((size_t)b * KK + k) * CC + c];
    }
#pragma unroll
    for (int b = 0; b < BB; ++b) {
#pragma unroll
        for (int off = 32; off > 0; off >>= 1)
            acc[b] += __shfl_down(acc[b], off, 64);
    }
    if (lane == 0) {
        const float bias = bf[k * CC + o];
#pragma unroll
        for (int b = 0; b < BB; ++b)
            fil[((size_t)b * KK + k) * CC + o] = acc[b] + bias;
    }
}

// ================= k_s4: pred = fil[b] @ x, fp32 out ==============
// x comes from xt4g: pre-swizzled 16KB tiles, read contiguously, raw LDS copy.
__global__ __launch_bounds__(256, 3) void k_s4(const unsigned short* __restrict__ xt4g,
                                               const float* __restrict__ fil,
                                               float* __restrict__ out) {
    __shared__ short wm[20 * CC];
    __shared__ short xt[2][128 * 64];
    const int tid = threadIdx.x;
    const int b = blockIdx.x >> 7;
    const int pt = blockIdx.x & 127;
    const int p0 = pt << 7;
    const float* fb = fil + ((size_t)b * KK) * CC;
    const unsigned short* tb = xt4g + ((size_t)((b << 7) | pt) << 16);

    for (int u = tid; u < 20 * 128; u += 256) {
        const int k = u >> 7;
        const int c4 = (u & 127) << 2;
        float4 w = {0.f, 0.f, 0.f, 0.f};
        if (k < KK) w = *(const float4*)(fb + k * CC + c4);
        s16x4 v = { (short)f2bf(w.x), (short)f2bf(w.y), (short)f2bf(w.z), (short)f2bf(w.w) };
        *(s16x4*)&wm[(k << 9) + (((c4 >> 3) ^ (k & 7)) << 3) + (c4 & 7)] = v;
    }

    const int wv = tid >> 6, ln = tid & 63;
    const int lm = ln & 15, q = ln >> 4;
    const f32x4 zz = {0.f, 0.f, 0.f, 0.f};
    f32x4 acc[2][2];
    acc[0][0] = zz; acc[0][1] = zz; acc[1][0] = zz; acc[1][1] = zz;

    uint4 Ta[4], Tb4[4];
#pragma unroll
    for (int r = 0; r < 4; ++r)
        Ta[r] = *(const uint4*)(tb + (r << 11) + (tid << 3));

#pragma unroll
    for (int cs = 0; cs < 8; ++cs) {
        const uint4* cur = (cs & 1) ? Tb4 : Ta;
        uint4* nxt = (cs & 1) ? Ta : Tb4;
        if (cs < 7) {                               // issue next tile EARLY
#pragma unroll
            for (int r = 0; r < 4; ++r)
                nxt[r] = *(const uint4*)(tb + ((size_t)(cs + 1) << 13) + (r << 11) + (tid << 3));
        }
        short* xts = (short*)xt[cs & 1];
#pragma unroll
        for (int r = 0; r < 4; ++r)
            *(uint4*)&xts[(r << 11) + (tid << 3)] = cur[r];
        asm volatile("s_waitcnt lgkmcnt(0)" ::: "memory");
        __builtin_amdgcn_s_barrier();
        asm volatile("" ::: "memory");
#pragma unroll
        for (int ks = 0; ks < 2; ++ks) {
            const int gch = (cs << 3) + (ks << 2) + q;
            const int m1 = (lm < 3) ? (16 + lm) : 19;
            bf16x8 a0 = *(const bf16x8*)&wm[(lm << 9) + ((gch ^ (lm & 7)) << 3)];
            bf16x8 a1 = *(const bf16x8*)&wm[(m1 << 9) + ((gch ^ (m1 & 7)) << 3)];
            const int lch = (ks << 2) + q;
#pragma unroll
            for (int nt = 0; nt < 2; ++nt) {
                const int pr = (((wv << 1) + nt) << 4) + lm;
                bf16x8 bv = *(const bf16x8*)&xts[(pr << 6) + ((lch ^ (pr & 7)) << 3)];
                acc[0][nt] = __builtin_amdgcn_mfma_f32_16x16x32_bf16(a0, bv, acc[0][nt], 0, 0, 0);
                acc[1][nt] = __builtin_amdgcn_mfma_f32_16x16x32_bf16(a1, bv, acc[1][nt], 0, 0, 0);
            }
        }
    }

    float* ob = out + ((size_t)b * KK) * HWHW + p0;
#pragma unroll
    for (int mt = 0; mt < 2; ++mt)
#pragma unroll
        for (int r = 0; r < 4; ++r) {
            const int k = (mt << 4) + (q << 2) + r;
            if (k < KK) {
#pragma unroll
                for (int nt = 0; nt < 2; ++nt) {
                    const int p = (((wv << 1) + nt) << 4) + lm;
                    ob[(size_t)k * HWHW + p] = acc[mt][nt][r];
                }
            }
        }
}

extern "C" void kernel_launch(void* const* d_in, const int* in_sizes, int n_in,
                              void* d_out, int out_size, void* d_ws, size_t ws_size,
                              hipStream_t stream) {
    const float* x  = (const float*)d_in[0];
    const float* Wm = (const float*)d_in[1];
    const float* bm = (const float*)d_in[2];
    const float* Wf = (const float*)d_in[3];
    const float* bf = (const float*)d_in[4];
    float* out = (float*)d_out;

    char* p = (char*)d_ws;
    unsigned short* mask = (unsigned short*)p;  p += (size_t)BB * KK * HWHW * 2;    // 4.98 MB
    float* cf_part = (float*)p;                 p += (size_t)16 * BB * KK * CC * 4;  // 4.98 MB
    float* cf  = (float*)p;                     p += (size_t)BB * KK * CC * 4;       // 311 KB
    float* fil = (float*)p;                     p += (size_t)BB * KK * CC * 4;       // 311 KB
    unsigned short* xt4g = (unsigned short*)p;                                       // 134 MB

    k_s1<<<1024, 256, 0, stream>>>(x, Wm, bm, mask, xt4g);
    k_s2<<<1024, 256, 0, stream>>>(xt4g, mask, cf_part);
    k_s2r<<<(BB * KK * CC + 255) / 256, 256, 0, stream>>>(cf_part, cf);
    k_filters<<<KK * 128, 256, 0, stream>>>(Wf, bf, cf, fil);
    k_s4<<<1024, 256, 0, stream>>>(xt4g, fil, out);
}

// Round 5
// 449.939 us; speedup vs baseline: 1.1236x; 1.0229x over previous
//
#include <hip/hip_runtime.h>
#include <math.h>

#define BB 8
#define CC 512
#define KK 19
#define HWHW 16384
#define INV_HW (1.0f/16384.0f)

typedef __attribute__((ext_vector_type(8))) short bf16x8;
typedef __attribute__((ext_vector_type(4))) short s16x4;
typedef __attribute__((ext_vector_type(4))) float f32x4;

__device__ __forceinline__ unsigned short f2bf(float f) {
    unsigned int u = __float_as_uint(f);
    u = (u + 0x7fffu + ((u >> 16) & 1u)) >> 16;
    return (unsigned short)u;
}

// pack 2 floats -> 2 bf16 (RNE, identical to f2bf) in one instruction
__device__ __forceinline__ unsigned int pk_bf16(float a, float b) {
    unsigned int r;
    asm("v_cvt_pk_bf16_f32 %0, %1, %2" : "=v"(r) : "v"(a), "v"(b));
    return r;
}

// ============ k_s12: FUSED mask-GEMM + sigmoid + masked pooling ============
// Per block: full 512c x 128p x-tile staged to LDS as 8 per-cs subtiles
// (16KB each, [p][c]-frag swizzled, single-buffered: distinct regions).
// Phase A: mask acc via MFMA + coalesced relay of each finished subtile to
// xt4g (byte image identical to R3, consumed by s4). Phase B: sigmoid ->
// bf16 mask tile in LDS -> pooling MFMA over K=p=128, B-frags gathered
// per-lane from this wave's own cs-subtile (cs == wv).
// mask is a dead intermediate -> never written to global.
// LDS: 128K(x) + 20K(wm) + 5K(mask) = 153KB -> 1 block/CU, 8 waves, 2/SIMD.
// Barriers: plain __syncthreads() (R1 proved counted-vmcnt machinery is
// perf-neutral on this problem; removes the only unproven sync pattern).
__global__ __launch_bounds__(512, 2) void k_s12(const float* __restrict__ x,
                                                const float* __restrict__ Wm,
                                                const float* __restrict__ bm,
                                                float* __restrict__ cf_part,
                                                unsigned short* __restrict__ xt4g) {
    __shared__ short wm[20 * CC];      // 20 KB
    __shared__ short xf[8 * 8192];     // 128 KB: 8 cs-subtiles of [128p][64c]
    __shared__ short mlds[20 * 128];   // 5 KB: mask [k][p] swizzled, row19=0
    const int tid = threadIdx.x;
    const int b = blockIdx.x >> 7;
    const int pt = blockIdx.x & 127;
    const float* xb = x + ((size_t)b * CC) * HWHW + (pt << 7);

    const int wv = tid >> 6, ln = tid & 63;
    const int lm = ln & 15, q = ln >> 4;

    // 2-deep prefetch: issue cs=0 and cs=1 loads FIRST
    const int cr0 = (tid >> 5) << 2;     // 0..60: base c-row within 64-chunk
    const int pA = (tid & 31) << 2;      // 0..124
    const int cg = tid >> 5;             // c-quad index 0..15
    const float* sbase = xb + (size_t)cr0 * HWHW + pA;

    float4 Fa[4], Fb[4], Fc[4];
#pragma unroll
    for (int j = 0; j < 4; ++j) Fa[j] = *(const float4*)(sbase + (size_t)j * HWHW);
#pragma unroll
    for (int j = 0; j < 4; ++j) Fb[j] = *(const float4*)(sbase + (size_t)(64 + j) * HWHW);

    // wm staging (overlaps load latency)
    for (int u = tid; u < 20 * 128; u += 512) {
        const int k = u >> 7;
        const int c4 = (u & 127) << 2;
        float4 w = {0.f, 0.f, 0.f, 0.f};
        if (k < KK) w = *(const float4*)(Wm + k * CC + c4);
        s16x4 v = { (short)f2bf(w.x), (short)f2bf(w.y), (short)f2bf(w.z), (short)f2bf(w.w) };
        *(s16x4*)&wm[(k << 9) + (((c4 >> 3) ^ (k & 7)) << 3) + (c4 & 7)] = v;
    }
    if (tid < 16)  // zero mask row 19 (read via clamped pad row in phase B)
        *(uint4*)&mlds[(19 << 7) + (tid << 3)] = make_uint4(0u, 0u, 0u, 0u);

    const f32x4 zz = {0.f, 0.f, 0.f, 0.f};
    f32x4 acc[2];
    acc[0] = zz; acc[1] = zz;

    unsigned short* t4fix = xt4g + ((size_t)((b << 7) | pt) << 16);

#pragma unroll
    for (int cs = 0; cs < 8; ++cs) {
        const float4* cur = (cs % 3 == 0) ? Fa : ((cs % 3 == 1) ? Fb : Fc);
        float4* nxt = ((cs + 2) % 3 == 0) ? Fa : (((cs + 2) % 3 == 1) ? Fb : Fc);
        if (cs < 6) {                              // issue cs+2 loads EARLY
            const size_t co = (size_t)((cs + 2) << 6) * HWHW;
#pragma unroll
            for (int j = 0; j < 4; ++j)
                nxt[j] = *(const float4*)(sbase + co + (size_t)j * HWHW);
        }
        short* xts = &xf[cs << 13];
        {
            const float* G0 = (const float*)&cur[0];
            const float* G1 = (const float*)&cur[1];
            const float* G2 = (const float*)&cur[2];
            const float* G3 = (const float*)&cur[3];
#pragma unroll
            for (int jj = 0; jj < 4; ++jj) {       // [p][c]-frag subtile
                const int pr = pA + jj;
                uint2 v = make_uint2(pk_bf16(G0[jj], G1[jj]), pk_bf16(G2[jj], G3[jj]));
                *(uint2*)&xts[(pr << 6) + (((cg >> 1) ^ (pr & 7)) << 3) + ((cg & 1) << 2)] = v;
            }
        }
        __syncthreads();
        // mask-GEMM MFMA: this wave's 16-p column slice
#pragma unroll
        for (int ks = 0; ks < 2; ++ks) {
            const int gch = (cs << 3) + (ks << 2) + q;
            const int m1 = (lm < 3) ? (16 + lm) : 19;
            bf16x8 a0 = *(const bf16x8*)&wm[(lm << 9) + ((gch ^ (lm & 7)) << 3)];
            bf16x8 a1 = *(const bf16x8*)&wm[(m1 << 9) + ((gch ^ (m1 & 7)) << 3)];
            const int lch = (ks << 2) + q;
            const int pr = (wv << 4) + lm;
            bf16x8 bv = *(const bf16x8*)&xts[(pr << 6) + ((lch ^ (pr & 7)) << 3)];
            acc[0] = __builtin_amdgcn_mfma_f32_16x16x32_bf16(a0, bv, acc[0], 0, 0, 0);
            acc[1] = __builtin_amdgcn_mfma_f32_16x16x32_bf16(a1, bv, acc[1], 0, 0, 0);
        }
        // coalesced relay of finished subtile: LDS image -> global (16KB)
        {
            unsigned short* t4 = t4fix + ((size_t)cs << 13);
#pragma unroll
            for (int r = 0; r < 2; ++r) {
                uint4 v = *(const uint4*)&xts[(r << 12) + (tid << 3)];
                *(uint4*)(t4 + (r << 12) + (tid << 3)) = v;
            }
        }
        __syncthreads();
    }

    // Phase B: sigmoid -> bf16 mask tile [k][p] (swizzled), then pooling
    {
        const int prow = (wv << 4) + lm;
#pragma unroll
        for (int mt = 0; mt < 2; ++mt)
#pragma unroll
            for (int r = 0; r < 4; ++r) {
                const int k = (mt << 4) + (q << 2) + r;
                if (k < KK) {
                    const float t = acc[mt][r] + bm[k];
                    const unsigned short mv = f2bf(1.0f / (1.0f + __expf(-t)));
                    mlds[(k << 7) + (((prow >> 3) ^ (k & 7)) << 3) + (prow & 7)] =
                        (short)mv;
                }
            }
    }
    __syncthreads();

    // pooling: D[k][c] += mask[k][p] * x[p][c], K=p=128. Wave wv owns
    // c in [wv*64, wv*64+64) -> gathers from its OWN subtile xf[wv].
    f32x4 pacc[2][4];
#pragma unroll
    for (int mt = 0; mt < 2; ++mt)
#pragma unroll
        for (int ct = 0; ct < 4; ++ct) pacc[mt][ct] = zz;

    const short* xw = &xf[wv << 13];
    const int m1 = (lm < 3) ? (16 + lm) : 19;
#pragma unroll
    for (int kp = 0; kp < 4; ++kp) {
        const int pg = (kp << 2) + q;
        bf16x8 a0 = *(const bf16x8*)&mlds[(lm << 7) + ((pg ^ (lm & 7)) << 3)];
        bf16x8 a1 = *(const bf16x8*)&mlds[(m1 << 7) + ((pg ^ (m1 & 7)) << 3)];
#pragma unroll
        for (int ct = 0; ct < 4; ++ct) {
            const int cl = (ct << 4) + lm;         // c_local 0..63
            short e[8];
#pragma unroll
            for (int i = 0; i < 8; ++i) {
                const int p = (kp << 5) + (q << 3) + i;
                e[i] = xw[(p << 6) + (((cl >> 3) ^ (p & 7)) << 3) + (cl & 7)];
            }
            bf16x8 bv = {e[0], e[1], e[2], e[3], e[4], e[5], e[6], e[7]};
            pacc[0][ct] = __builtin_amdgcn_mfma_f32_16x16x32_bf16(a0, bv, pacc[0][ct], 0, 0, 0);
            pacc[1][ct] = __builtin_amdgcn_mfma_f32_16x16x32_bf16(a1, bv, pacc[1][ct], 0, 0, 0);
        }
    }

    float* dst = cf_part + ((size_t)pt * BB + b) * KK * CC;
#pragma unroll
    for (int mt = 0; mt < 2; ++mt)
#pragma unroll
        for (int r = 0; r < 4; ++r) {
            const int k = (mt << 4) + (q << 2) + r;
            if (k < KK) {
#pragma unroll
                for (int ct = 0; ct < 4; ++ct)
                    dst[k * CC + (wv << 6) + (ct << 4) + lm] = pacc[mt][ct][r];
            }
        }
}

// ========== k_s2r: cf = INV_HW * sum_pt cf_part (128 partials) ==========
__global__ __launch_bounds__(256) void k_s2r(const float* __restrict__ part,
                                             float* __restrict__ cf) {
    const int i = blockIdx.x * 256 + threadIdx.x;
    if (i >= BB * KK * CC) return;
    const int b = i / (KK * CC);
    const int rem = i - b * (KK * CC);
    float sum = 0.0f;
#pragma unroll 8
    for (int pt = 0; pt < 128; ++pt)
        sum += part[((size_t)pt * BB + b) * KK * CC + rem];
    cf[i] = sum * INV_HW;
}

// ====== k_filters: fil[b,k,o] = sum_c Wf[k,o,c]*cf[b,k,c] + bf[k,o] ======
__global__ __launch_bounds__(256) void k_filters(const float* __restrict__ Wf,
                                                 const float* __restrict__ bf,
                                                 const float* __restrict__ cf,
                                                 float* __restrict__ fil) {
    const int blk = blockIdx.x;
    const int k = blk >> 7;
    const int o = ((blk & 127) << 2) + (threadIdx.x >> 6);
    const int lane = threadIdx.x & 63;
    const float* wrow = Wf + ((size_t)k * CC + o) * CC;

    float acc[BB];
#pragma unroll
    for (int b = 0; b < BB; ++b) acc[b] = 0.0f;
#pragma unroll
    for (int j = 0; j < CC / 64; ++j) {
        const int c = lane + (j << 6);
        const float wv = wrow[c];
#pragma unroll
        for (int b = 0; b < BB; ++b)
            acc[b] += wv * cf[((size_t)b * KK + k) * CC + c];
    }
#pragma unroll
    for (int b = 0; b < BB; ++b) {
#pragma unroll
        for (int off = 32; off > 0; off >>= 1)
            acc[b] += __shfl_down(acc[b], off, 64);
    }
    if (lane == 0) {
        const float bias = bf[k * CC + o];
#pragma unroll
        for (int b = 0; b < BB; ++b)
            fil[((size_t)b * KK + k) * CC + o] = acc[b] + bias;
    }
}

// ================= k_s4: pred = fil[b] @ x, fp32 out ==============
// x comes from xt4g: pre-swizzled 16KB tiles, read contiguously, raw LDS copy.
__global__ __launch_bounds__(256, 3) void k_s4(const unsigned short* __restrict__ xt4g,
                                               const float* __restrict__ fil,
                                               float* __restrict__ out) {
    __shared__ short wm[20 * CC];
    __shared__ short xt[2][128 * 64];
    const int tid = threadIdx.x;
    const int b = blockIdx.x >> 7;
    const int pt = blockIdx.x & 127;
    const int p0 = pt << 7;
    const float* fb = fil + ((size_t)b * KK) * CC;
    const unsigned short* tb = xt4g + ((size_t)((b << 7) | pt) << 16);

    for (int u = tid; u < 20 * 128; u += 256) {
        const int k = u >> 7;
        const int c4 = (u & 127) << 2;
        float4 w = {0.f, 0.f, 0.f, 0.f};
        if (k < KK) w = *(const float4*)(fb + k * CC + c4);
        s16x4 v = { (short)f2bf(w.x), (short)f2bf(w.y), (short)f2bf(w.z), (short)f2bf(w.w) };
        *(s16x4*)&wm[(k << 9) + (((c4 >> 3) ^ (k & 7)) << 3) + (c4 & 7)] = v;
    }

    const int wv = tid >> 6, ln = tid & 63;
    const int lm = ln & 15, q = ln >> 4;
    const f32x4 zz = {0.f, 0.f, 0.f, 0.f};
    f32x4 acc[2][2];
    acc[0][0] = zz; acc[0][1] = zz; acc[1][0] = zz; acc[1][1] = zz;

    uint4 Ta[4], Tb4[4];
#pragma unroll
    for (int r = 0; r < 4; ++r)
        Ta[r] = *(const uint4*)(tb + (r << 11) + (tid << 3));

#pragma unroll
    for (int cs = 0; cs < 8; ++cs) {
        const uint4* cur = (cs & 1) ? Tb4 : Ta;
        uint4* nxt = (cs & 1) ? Ta : Tb4;
        if (cs < 7) {                               // issue next tile EARLY
#pragma unroll
            for (int r = 0; r < 4; ++r)
                nxt[r] = *(const uint4*)(tb + ((size_t)(cs + 1) << 13) + (r << 11) + (tid << 3));
        }
        short* xts = (short*)xt[cs & 1];
#pragma unroll
        for (int r = 0; r < 4; ++r)
            *(uint4*)&xts[(r << 11) + (tid << 3)] = cur[r];
        asm volatile("s_waitcnt lgkmcnt(0)" ::: "memory");
        __builtin_amdgcn_s_barrier();
        asm volatile("" ::: "memory");
#pragma unroll
        for (int ks = 0; ks < 2; ++ks) {
            const int gch = (cs << 3) + (ks << 2) + q;
            const int m1 = (lm < 3) ? (16 + lm) : 19;
            bf16x8 a0 = *(const bf16x8*)&wm[(lm << 9) + ((gch ^ (lm & 7)) << 3)];
            bf16x8 a1 = *(const bf16x8*)&wm[(m1 << 9) + ((gch ^ (m1 & 7)) << 3)];
            const int lch = (ks << 2) + q;
#pragma unroll
            for (int nt = 0; nt < 2; ++nt) {
                const int pr = (((wv << 1) + nt) << 4) + lm;
                bf16x8 bv = *(const bf16x8*)&xts[(pr << 6) + ((lch ^ (pr & 7)) << 3)];
                acc[0][nt] = __builtin_amdgcn_mfma_f32_16x16x32_bf16(a0, bv, acc[0][nt], 0, 0, 0);
                acc[1][nt] = __builtin_amdgcn_mfma_f32_16x16x32_bf16(a1, bv, acc[1][nt], 0, 0, 0);
            }
        }
    }

    float* ob = out + ((size_t)b * KK) * HWHW + p0;
#pragma unroll
    for (int mt = 0; mt < 2; ++mt)
#pragma unroll
        for (int r = 0; r < 4; ++r) {
            const int k = (mt << 4) + (q << 2) + r;
            if (k < KK) {
#pragma unroll
                for (int nt = 0; nt < 2; ++nt) {
                    const int p = (((wv << 1) + nt) << 4) + lm;
                    ob[(size_t)k * HWHW + p] = acc[mt][nt][r];
                }
            }
        }
}

extern "C" void kernel_launch(void* const* d_in, const int* in_sizes, int n_in,
                              void* d_out, int out_size, void* d_ws, size_t ws_size,
                              hipStream_t stream) {
    const float* x  = (const float*)d_in[0];
    const float* Wm = (const float*)d_in[1];
    const float* bm = (const float*)d_in[2];
    const float* Wf = (const float*)d_in[3];
    const float* bf = (const float*)d_in[4];
    float* out = (float*)d_out;

    char* p = (char*)d_ws;
    float* cf_part = (float*)p;                 p += (size_t)128 * BB * KK * CC * 4; // 39.8 MB
    float* cf  = (float*)p;                     p += (size_t)BB * KK * CC * 4;       // 311 KB
    float* fil = (float*)p;                     p += (size_t)BB * KK * CC * 4;       // 311 KB
    unsigned short* xt4g = (unsigned short*)p;                                       // 134 MB

    k_s12<<<1024, 512, 0, stream>>>(x, Wm, bm, cf_part, xt4g);
    k_s2r<<<(BB * KK * CC + 255) / 256, 256, 0, stream>>>(cf_part, cf);
    k_filters<<<KK * 128, 256, 0, stream>>>(Wf, bf, cf, fil);
    k_s4<<<1024, 256, 0, stream>>>(xt4g, fil, out);
}